// Round 7
// baseline (887.868 us; speedup 1.0000x reference)
//
#include <hip/hip_runtime.h>

#define F_IN 64
#define NH 4
#define HC 128
#define NEG_SLOPE 0.2f
#define LN_EPS 1e-5f
#define NC_CHUNK 128          // number of edge chunks (and stride of counts matrix)
#define BUCKET 128            // dst nodes per bucket

// ---------------------------------------------------------------------------
// K0: detect whether edge_index arrived as int64 (little-endian) or int32.
// ---------------------------------------------------------------------------
__global__ void k0_detect(const int* __restrict__ ei, int E, int* __restrict__ flag) {
    __shared__ int any_nz;
    if (threadIdx.x == 0) any_nz = 0;
    __syncthreads();
    long long stride = (2LL * E) / 257;
    long long pos = (long long)(threadIdx.x + 1) * stride;
    int w = ei[pos | 1];
    if (w != 0) atomicOr(&any_nz, 1);
    __syncthreads();
    if (threadIdx.x == 0) flag[0] = (any_nz == 0) ? 1 : 0;   // 1 => int64
}

__device__ inline unsigned bfpack(float a, float b) {
    unsigned ua = __float_as_uint(a), ub = __float_as_uint(b);
    ua = (ua + 0x7fffu + ((ua >> 16) & 1u)) >> 16;           // RNE to bf16
    ub = (ub + 0x7fffu + ((ub >> 16) & 1u)) >> 16;
    return ua | (ub << 16);
}

__device__ inline float wave_bcast_sum(float v) {
#pragma unroll
    for (int off = 32; off > 0; off >>= 1) v += __shfl_down(v, off, 64);
    return __shfl(v, 0, 64);
}

// ---------------------------------------------------------------------------
// KA: fused dual GEMM: h_bf16 = x@W (rounded), r = x@res_w, plus attention
// logits a_s/a_d from f32 accumulators. (unchanged from R5 — proven)
// ---------------------------------------------------------------------------
#define NT 64
#define XS_LD 66
__global__ __launch_bounds__(256) void kA_gemm(
    const float* __restrict__ x, const float* __restrict__ W,
    const float* __restrict__ res_w,
    const float* __restrict__ att_src, const float* __restrict__ att_dst,
    unsigned int* __restrict__ h_bf, float* __restrict__ r,
    float* __restrict__ a_s, float* __restrict__ a_d, int n)
{
    __shared__ float Ws[F_IN * HC];
    __shared__ float xs[NT * XS_LD];
    int tid = threadIdx.x;
    int j = tid & 15, i = tid >> 4;
    int nb0 = blockIdx.x * NT;

#pragma unroll
    for (int it = 0; it < 8; ++it) {
        int f2 = it * 256 + tid;
        int node = f2 >> 5, k2 = f2 & 31;
        int src = nb0 + node; if (src >= n) src = n - 1;
        float2 v = *(const float2*)&x[src * F_IN + k2 * 2];
        xs[node * XS_LD + k2 * 2]     = v.x;
        xs[node * XS_LD + k2 * 2 + 1] = v.y;
    }

    for (int half = 0; half < 2; ++half) {
        __syncthreads();
        {
            const float4* src4 = (const float4*)(half ? res_w : W);
            float4* Ws4 = (float4*)Ws;
            for (int it = tid; it < F_IN * HC / 4; it += 256) Ws4[it] = src4[it];
        }
        __syncthreads();

        for (int cg = 0; cg < 2; ++cg) {
            float acc[4][4];
#pragma unroll
            for (int m = 0; m < 4; ++m)
#pragma unroll
                for (int c = 0; c < 4; ++c) acc[m][c] = 0.f;

            const float* wbase = &Ws[cg * 64 + j * 4];
            const float* xbase = &xs[(i * 4) * XS_LD];
#pragma unroll 8
            for (int k2 = 0; k2 < 32; ++k2) {
                float2 xv0 = *(const float2*)&xbase[0 * XS_LD + 2 * k2];
                float2 xv1 = *(const float2*)&xbase[1 * XS_LD + 2 * k2];
                float2 xv2 = *(const float2*)&xbase[2 * XS_LD + 2 * k2];
                float2 xv3 = *(const float2*)&xbase[3 * XS_LD + 2 * k2];
                float4 w0 = *(const float4*)&wbase[(2 * k2) * HC];
                float4 w1 = *(const float4*)&wbase[(2 * k2 + 1) * HC];
                acc[0][0] += xv0.x * w0.x + xv0.y * w1.x;
                acc[0][1] += xv0.x * w0.y + xv0.y * w1.y;
                acc[0][2] += xv0.x * w0.z + xv0.y * w1.z;
                acc[0][3] += xv0.x * w0.w + xv0.y * w1.w;
                acc[1][0] += xv1.x * w0.x + xv1.y * w1.x;
                acc[1][1] += xv1.x * w0.y + xv1.y * w1.y;
                acc[1][2] += xv1.x * w0.z + xv1.y * w1.z;
                acc[1][3] += xv1.x * w0.w + xv1.y * w1.w;
                acc[2][0] += xv2.x * w0.x + xv2.y * w1.x;
                acc[2][1] += xv2.x * w0.y + xv2.y * w1.y;
                acc[2][2] += xv2.x * w0.z + xv2.y * w1.z;
                acc[2][3] += xv2.x * w0.w + xv2.y * w1.w;
                acc[3][0] += xv3.x * w0.x + xv3.y * w1.x;
                acc[3][1] += xv3.x * w0.y + xv3.y * w1.y;
                acc[3][2] += xv3.x * w0.z + xv3.y * w1.z;
                acc[3][3] += xv3.x * w0.w + xv3.y * w1.w;
            }

            if (half == 0) {
                float4 asv = *(const float4*)&att_src[cg * 64 + j * 4];
                float4 adv = *(const float4*)&att_dst[cg * 64 + j * 4];
                int head = cg * 2 + (j >> 3);
#pragma unroll
                for (int m = 0; m < 4; ++m) {
                    int node = nb0 + i * 4 + m;
                    float vs = acc[m][0] * asv.x + acc[m][1] * asv.y
                             + acc[m][2] * asv.z + acc[m][3] * asv.w;
                    float vd = acc[m][0] * adv.x + acc[m][1] * adv.y
                             + acc[m][2] * adv.z + acc[m][3] * adv.w;
                    vs += __shfl_down(vs, 4, 8); vd += __shfl_down(vd, 4, 8);
                    vs += __shfl_down(vs, 2, 8); vd += __shfl_down(vd, 2, 8);
                    vs += __shfl_down(vs, 1, 8); vd += __shfl_down(vd, 1, 8);
                    if (node < n) {
                        if ((j & 7) == 0) {
                            a_s[node * NH + head] = vs;
                            a_d[node * NH + head] = vd;
                        }
                        uint2 p = make_uint2(bfpack(acc[m][0], acc[m][1]),
                                             bfpack(acc[m][2], acc[m][3]));
                        *(uint2*)&h_bf[node * 64 + cg * 32 + j * 2] = p;
                    }
                }
            } else {
#pragma unroll
                for (int m = 0; m < 4; ++m) {
                    int node = nb0 + i * 4 + m;
                    if (node < n)
                        *(float4*)&r[node * HC + cg * 64 + j * 4] =
                            make_float4(acc[m][0], acc[m][1], acc[m][2], acc[m][3]);
                }
            }
        }
    }
}

// ---------------------------------------------------------------------------
// KC_count: chunk c histograms ITS OWN edges by dst bucket (LDS), writes
// counts[b][c]. No redundant reads, no global atomics.
// ---------------------------------------------------------------------------
__global__ __launch_bounds__(256) void kc_count(
    const int* __restrict__ ei, int E, const int* __restrict__ flag,
    int* __restrict__ counts, int NB, int chunk)
{
    __shared__ int cnt[512];
    int c = blockIdx.x;
    for (int i = threadIdx.x; i < NB; i += 256) cnt[i] = 0;
    __syncthreads();
    int base = c * chunk, end = min(E, base + chunk);
    int is64 = flag[0];
    for (int idx = base + threadIdx.x; idx < end; idx += 256) {
        int d = is64 ? ei[2 * (E + idx)] : ei[E + idx];
        atomicAdd(&cnt[d >> 7], 1);
    }
    __syncthreads();
    for (int b = threadIdx.x; b < NB; b += 256)
        counts[b * NC_CHUNK + c] = cnt[b];
}

// ---------------------------------------------------------------------------
// 3-phase exclusive scan over M = NB*NC_CHUNK elements, in place.
// ---------------------------------------------------------------------------
__global__ __launch_bounds__(256) void k_scan_p1(const int* __restrict__ arr, int M,
                                                 int* __restrict__ bsums)
{
    __shared__ int red[4];
    int i = blockIdx.x * 256 + threadIdx.x;
    int v = (i < M) ? arr[i] : 0;
#pragma unroll
    for (int off = 32; off > 0; off >>= 1) v += __shfl_down(v, off, 64);
    int lane = threadIdx.x & 63, wv = threadIdx.x >> 6;
    if (lane == 0) red[wv] = v;
    __syncthreads();
    if (threadIdx.x == 0)
        bsums[blockIdx.x] = red[0] + red[1] + red[2] + red[3];
}

__global__ __launch_bounds__(256) void k_scan_p2(int* __restrict__ bsums, int nblk)
{
    __shared__ int sh[256];
    int t = threadIdx.x;
    int v = (t < nblk) ? bsums[t] : 0;
    sh[t] = v;
    __syncthreads();
#pragma unroll
    for (int off = 1; off < 256; off <<= 1) {
        int u = (t >= off) ? sh[t - off] : 0;
        __syncthreads();
        sh[t] += u;
        __syncthreads();
    }
    if (t < nblk) bsums[t] = sh[t] - v;
}

__global__ __launch_bounds__(256) void k_scan_p3(int* __restrict__ arr,
                                                 const int* __restrict__ bsums,
                                                 int M, int E)
{
    __shared__ int sh[256];
    int t = threadIdx.x;
    int i = blockIdx.x * 256 + t;
    int v = (i < M) ? arr[i] : 0;
    sh[t] = v;
    __syncthreads();
#pragma unroll
    for (int off = 1; off < 256; off <<= 1) {
        int u = (t >= off) ? sh[t - off] : 0;
        __syncthreads();
        sh[t] += u;
        __syncthreads();
    }
    int excl = sh[t] - v + bsums[blockIdx.x];
    if (i < M) arr[i] = excl;
    if (blockIdx.x == 0 && t == 0) arr[M] = E;
}

// ---------------------------------------------------------------------------
// KC_scatter: chunk c re-reads its edges, writes packed (dst_local<<16 | src)
// into its private per-bucket slices (LDS cursors). Requires n <= 65536.
// ---------------------------------------------------------------------------
__global__ __launch_bounds__(1024) void kc_scatter(
    const int* __restrict__ ei, int E, const int* __restrict__ flag,
    const int* __restrict__ off, int NB, int chunk, int* __restrict__ epacked)
{
    __shared__ int cur[512];
    int c = blockIdx.x;
    for (int b = threadIdx.x; b < NB; b += 1024) cur[b] = off[b * NC_CHUNK + c];
    __syncthreads();
    int base = c * chunk, end = min(E, base + chunk);
    int is64 = flag[0];
    for (int idx = base + threadIdx.x; idx < end; idx += 1024) {
        int s = is64 ? ei[2 * idx] : ei[idx];
        int d = is64 ? ei[2 * (E + idx)] : ei[E + idx];
        int p = atomicAdd(&cur[d >> 7], 1);
        epacked[p] = ((d & (BUCKET - 1)) << 16) | s;
    }
}

// ---------------------------------------------------------------------------
// KD_agg: one block per bucket of 128 dsts. Reads its contiguous packed edge
// slice, accumulates softmax-weighted messages into LDS (float atomics),
// then runs the fused epilogue (self-loop, bias, ELU, residual, LN) in place.
// LDS = 64KB accum + 2KB dsum + 2KB adl => 2 blocks/CU.
// ---------------------------------------------------------------------------
__global__ __launch_bounds__(1024) void kd_agg(
    const int* __restrict__ off, const int* __restrict__ epacked,
    const float* __restrict__ a_s, const float* __restrict__ a_d,
    const unsigned int* __restrict__ h_bf, const float* __restrict__ r,
    const float* __restrict__ bias, const float* __restrict__ res_b,
    const float* __restrict__ ln_g, const float* __restrict__ ln_b,
    float* __restrict__ out, int n)
{
    __shared__ float accum[BUCKET * HC];     // 64 KB
    __shared__ float dsum[BUCKET * NH];      // 2 KB
    __shared__ float adl[BUCKET * NH];       // 2 KB
    int b = blockIdx.x;
    int b0 = b * BUCKET;
    int nb_local = min(BUCKET, n - b0);
    int tid = threadIdx.x;

    for (int i = tid; i < BUCKET * HC; i += 1024) accum[i] = 0.f;
    for (int i = tid; i < BUCKET * NH; i += 1024) dsum[i] = 0.f;
    for (int i = tid; i < nb_local * NH; i += 1024) adl[i] = a_d[b0 * NH + i];
    __syncthreads();

    int estart = off[b * NC_CHUNK];
    int eend   = off[(b + 1) * NC_CHUNK];    // last bucket: off[M] == E
    int grp = tid >> 6, lane = tid & 63;
    int head = lane >> 4;

    for (int e = estart + grp; e < eend; e += 16) {
        int packed = epacked[e];             // wave-uniform load (broadcast)
        int s  = packed & 0xFFFF;
        int dl = packed >> 16;
        float ev = a_s[s * NH + head] + adl[dl * NH + head];
        ev = (ev >= 0.f) ? ev : NEG_SLOPE * ev;
        float w = __expf(ev);
        unsigned hv = h_bf[s * 64 + lane];
        atomicAdd(&accum[dl * HC + 2 * lane],     w * __uint_as_float(hv << 16));
        atomicAdd(&accum[dl * HC + 2 * lane + 1], w * __uint_as_float(hv & 0xffff0000u));
        if ((lane & 15) == 0) atomicAdd(&dsum[dl * NH + head], w);
    }
    __syncthreads();

    int c0 = lane * 2;
    for (int dl = grp; dl < nb_local; dl += 16) {    // wave-uniform dl
        int d = b0 + dl;
        float es = a_s[d * NH + head] + adl[dl * NH + head];
        es = (es >= 0.f) ? es : NEG_SLOPE * es;
        float ws = __expf(es);                       // self-loop weight
        unsigned hv = h_bf[d * 64 + lane];
        float nx = accum[dl * HC + c0]     + ws * __uint_as_float(hv << 16);
        float ny = accum[dl * HC + c0 + 1] + ws * __uint_as_float(hv & 0xffff0000u);
        float inv = 1.f / (dsum[dl * NH + head] + ws);
        float ox = nx * inv + bias[c0];
        float oy = ny * inv + bias[c0 + 1];
        ox = (ox > 0.f) ? ox : expm1f(ox);
        oy = (oy > 0.f) ? oy : expm1f(oy);
        float2 rv = *(const float2*)&r[d * HC + c0];
        ox += rv.x + res_b[c0];
        oy += rv.y + res_b[c0 + 1];
        float mean = wave_bcast_sum(ox + oy) * (1.f / HC);
        float dx = ox - mean, dy = oy - mean;
        float var = wave_bcast_sum(dx * dx + dy * dy) * (1.f / HC);
        float rs = rsqrtf(var + LN_EPS);
        *(float2*)&out[d * HC + c0] =
            make_float2(ln_g[c0] * dx * rs + ln_b[c0],
                        ln_g[c0 + 1] * dy * rs + ln_b[c0 + 1]);
    }
}

// ---------------------------------------------------------------------------
extern "C" void kernel_launch(void* const* d_in, const int* in_sizes, int n_in,
                              void* d_out, int out_size, void* d_ws, size_t ws_size,
                              hipStream_t stream) {
    const float* x       = (const float*)d_in[0];
    const int*   ei      = (const int*)d_in[1];
    const float* W       = (const float*)d_in[2];
    const float* att_src = (const float*)d_in[3];
    const float* att_dst = (const float*)d_in[4];
    const float* bias    = (const float*)d_in[5];
    const float* res_w   = (const float*)d_in[6];
    const float* res_b   = (const float*)d_in[7];
    const float* ln_g    = (const float*)d_in[8];
    const float* ln_b    = (const float*)d_in[9];
    float* out = (float*)d_out;

    int n = in_sizes[0] / F_IN;              // 50000 (must be <= 65536 for packing)
    int E = in_sizes[1] / 2;                 // 800000
    int NB = (n + BUCKET - 1) / BUCKET;      // 391 buckets (<= 512)
    int chunk = (E + NC_CHUNK - 1) / NC_CHUNK;
    int M = NB * NC_CHUNK;                   // 50048
    int nblk = (M + 255) / 256;              // 196 (<= 256)

    float*    r       = (float*)d_ws;                     // n*HC f32
    unsigned* h_bf    = (unsigned*)(r + (size_t)n * HC);  // n*64 dwords
    float*    a_s     = (float*)(h_bf + (size_t)n * 64);  // n*NH
    float*    a_d     = a_s + (size_t)n * NH;             // n*NH
    int*      off     = (int*)(a_d + (size_t)n * NH);     // M+1 (counts -> offsets)
    int*      bsums   = off + (M + 1);                    // 256
    int*      epacked = bsums + 256;                      // E
    int*      flag    = epacked + E;                      // 1

    k0_detect<<<1, 256, 0, stream>>>(ei, E, flag);

    kA_gemm<<<(n + NT - 1) / NT, 256, 0, stream>>>(
        x, W, res_w, att_src, att_dst, h_bf, r, a_s, a_d, n);

    kc_count<<<NC_CHUNK, 256, 0, stream>>>(ei, E, flag, off, NB, chunk);

    k_scan_p1<<<nblk, 256, 0, stream>>>(off, M, bsums);
    k_scan_p2<<<1, 256, 0, stream>>>(bsums, nblk);
    k_scan_p3<<<nblk, 256, 0, stream>>>(off, bsums, M, E);

    kc_scatter<<<NC_CHUNK, 1024, 0, stream>>>(ei, E, flag, off, NB, chunk, epacked);

    kd_agg<<<NB, 1024, 0, stream>>>(off, epacked, a_s, a_d, h_bf, r,
                                    bias, res_b, ln_g, ln_b, out, n);
}

// Round 8
// 218.221 us; speedup vs baseline: 4.0687x; 4.0687x over previous
//
#include <hip/hip_runtime.h>

#define F_IN 64
#define NH 4
#define HC 128
#define NEG_SLOPE 0.2f
#define LN_EPS 1e-5f
#define NC_CHUNK 128          // number of edge chunks
#define BUCKET 128            // dst nodes per bucket

// ---------------------------------------------------------------------------
// K0: detect whether edge_index arrived as int64 (little-endian) or int32.
// ---------------------------------------------------------------------------
__global__ void k0_detect(const int* __restrict__ ei, int E, int* __restrict__ flag) {
    __shared__ int any_nz;
    if (threadIdx.x == 0) any_nz = 0;
    __syncthreads();
    long long stride = (2LL * E) / 257;
    long long pos = (long long)(threadIdx.x + 1) * stride;
    int w = ei[pos | 1];
    if (w != 0) atomicOr(&any_nz, 1);
    __syncthreads();
    if (threadIdx.x == 0) flag[0] = (any_nz == 0) ? 1 : 0;   // 1 => int64
}

__device__ inline unsigned bfpack(float a, float b) {
    unsigned ua = __float_as_uint(a), ub = __float_as_uint(b);
    ua = (ua + 0x7fffu + ((ua >> 16) & 1u)) >> 16;           // RNE to bf16
    ub = (ub + 0x7fffu + ((ub >> 16) & 1u)) >> 16;
    return ua | (ub << 16);
}

__device__ inline float wave_bcast_sum(float v) {
#pragma unroll
    for (int off = 32; off > 0; off >>= 1) v += __shfl_down(v, off, 64);
    return __shfl(v, 0, 64);
}

// ---------------------------------------------------------------------------
// KA: fused dual GEMM (unchanged, proven): h_bf16 = x@W, r = x@res_w, logits.
// ---------------------------------------------------------------------------
#define NT 64
#define XS_LD 66
__global__ __launch_bounds__(256) void kA_gemm(
    const float* __restrict__ x, const float* __restrict__ W,
    const float* __restrict__ res_w,
    const float* __restrict__ att_src, const float* __restrict__ att_dst,
    unsigned int* __restrict__ h_bf, float* __restrict__ r,
    float* __restrict__ a_s, float* __restrict__ a_d, int n)
{
    __shared__ float Ws[F_IN * HC];
    __shared__ float xs[NT * XS_LD];
    int tid = threadIdx.x;
    int j = tid & 15, i = tid >> 4;
    int nb0 = blockIdx.x * NT;

#pragma unroll
    for (int it = 0; it < 8; ++it) {
        int f2 = it * 256 + tid;
        int node = f2 >> 5, k2 = f2 & 31;
        int src = nb0 + node; if (src >= n) src = n - 1;
        float2 v = *(const float2*)&x[src * F_IN + k2 * 2];
        xs[node * XS_LD + k2 * 2]     = v.x;
        xs[node * XS_LD + k2 * 2 + 1] = v.y;
    }

    for (int half = 0; half < 2; ++half) {
        __syncthreads();
        {
            const float4* src4 = (const float4*)(half ? res_w : W);
            float4* Ws4 = (float4*)Ws;
            for (int it = tid; it < F_IN * HC / 4; it += 256) Ws4[it] = src4[it];
        }
        __syncthreads();

        for (int cg = 0; cg < 2; ++cg) {
            float acc[4][4];
#pragma unroll
            for (int m = 0; m < 4; ++m)
#pragma unroll
                for (int c = 0; c < 4; ++c) acc[m][c] = 0.f;

            const float* wbase = &Ws[cg * 64 + j * 4];
            const float* xbase = &xs[(i * 4) * XS_LD];
#pragma unroll 8
            for (int k2 = 0; k2 < 32; ++k2) {
                float2 xv0 = *(const float2*)&xbase[0 * XS_LD + 2 * k2];
                float2 xv1 = *(const float2*)&xbase[1 * XS_LD + 2 * k2];
                float2 xv2 = *(const float2*)&xbase[2 * XS_LD + 2 * k2];
                float2 xv3 = *(const float2*)&xbase[3 * XS_LD + 2 * k2];
                float4 w0 = *(const float4*)&wbase[(2 * k2) * HC];
                float4 w1 = *(const float4*)&wbase[(2 * k2 + 1) * HC];
                acc[0][0] += xv0.x * w0.x + xv0.y * w1.x;
                acc[0][1] += xv0.x * w0.y + xv0.y * w1.y;
                acc[0][2] += xv0.x * w0.z + xv0.y * w1.z;
                acc[0][3] += xv0.x * w0.w + xv0.y * w1.w;
                acc[1][0] += xv1.x * w0.x + xv1.y * w1.x;
                acc[1][1] += xv1.x * w0.y + xv1.y * w1.y;
                acc[1][2] += xv1.x * w0.z + xv1.y * w1.z;
                acc[1][3] += xv1.x * w0.w + xv1.y * w1.w;
                acc[2][0] += xv2.x * w0.x + xv2.y * w1.x;
                acc[2][1] += xv2.x * w0.y + xv2.y * w1.y;
                acc[2][2] += xv2.x * w0.z + xv2.y * w1.z;
                acc[2][3] += xv2.x * w0.w + xv2.y * w1.w;
                acc[3][0] += xv3.x * w0.x + xv3.y * w1.x;
                acc[3][1] += xv3.x * w0.y + xv3.y * w1.y;
                acc[3][2] += xv3.x * w0.z + xv3.y * w1.z;
                acc[3][3] += xv3.x * w0.w + xv3.y * w1.w;
            }

            if (half == 0) {
                float4 asv = *(const float4*)&att_src[cg * 64 + j * 4];
                float4 adv = *(const float4*)&att_dst[cg * 64 + j * 4];
                int head = cg * 2 + (j >> 3);
#pragma unroll
                for (int m = 0; m < 4; ++m) {
                    int node = nb0 + i * 4 + m;
                    float vs = acc[m][0] * asv.x + acc[m][1] * asv.y
                             + acc[m][2] * asv.z + acc[m][3] * asv.w;
                    float vd = acc[m][0] * adv.x + acc[m][1] * adv.y
                             + acc[m][2] * adv.z + acc[m][3] * adv.w;
                    vs += __shfl_down(vs, 4, 8); vd += __shfl_down(vd, 4, 8);
                    vs += __shfl_down(vs, 2, 8); vd += __shfl_down(vd, 2, 8);
                    vs += __shfl_down(vs, 1, 8); vd += __shfl_down(vd, 1, 8);
                    if (node < n) {
                        if ((j & 7) == 0) {
                            a_s[node * NH + head] = vs;
                            a_d[node * NH + head] = vd;
                        }
                        uint2 p = make_uint2(bfpack(acc[m][0], acc[m][1]),
                                             bfpack(acc[m][2], acc[m][3]));
                        *(uint2*)&h_bf[node * 64 + cg * 32 + j * 2] = p;
                    }
                }
            } else {
#pragma unroll
                for (int m = 0; m < 4; ++m) {
                    int node = nb0 + i * 4 + m;
                    if (node < n)
                        *(float4*)&r[node * HC + cg * 64 + j * 4] =
                            make_float4(acc[m][0], acc[m][1], acc[m][2], acc[m][3]);
                }
            }
        }
    }
}

// ---------------------------------------------------------------------------
// KC_count: chunk c histograms ITS OWN edges by dst bucket (LDS).
// ---------------------------------------------------------------------------
__global__ __launch_bounds__(256) void kc_count(
    const int* __restrict__ ei, int E, const int* __restrict__ flag,
    int* __restrict__ counts, int NB, int chunk)
{
    __shared__ int cnt[512];
    int c = blockIdx.x;
    for (int i = threadIdx.x; i < NB; i += 256) cnt[i] = 0;
    __syncthreads();
    int base = c * chunk, end = min(E, base + chunk);
    int is64 = flag[0];
    for (int idx = base + threadIdx.x; idx < end; idx += 256) {
        int d = is64 ? ei[2 * (E + idx)] : ei[E + idx];
        atomicAdd(&cnt[d >> 7], 1);
    }
    __syncthreads();
    for (int b = threadIdx.x; b < NB; b += 256)
        counts[b * NC_CHUNK + c] = cnt[b];
}

// ---------------------------------------------------------------------------
// 3-phase exclusive scan over M = NB*NC_CHUNK elements, in place.
// ---------------------------------------------------------------------------
__global__ __launch_bounds__(256) void k_scan_p1(const int* __restrict__ arr, int M,
                                                 int* __restrict__ bsums)
{
    __shared__ int red[4];
    int i = blockIdx.x * 256 + threadIdx.x;
    int v = (i < M) ? arr[i] : 0;
#pragma unroll
    for (int off = 32; off > 0; off >>= 1) v += __shfl_down(v, off, 64);
    int lane = threadIdx.x & 63, wv = threadIdx.x >> 6;
    if (lane == 0) red[wv] = v;
    __syncthreads();
    if (threadIdx.x == 0)
        bsums[blockIdx.x] = red[0] + red[1] + red[2] + red[3];
}

__global__ __launch_bounds__(256) void k_scan_p2(int* __restrict__ bsums, int nblk)
{
    __shared__ int sh[256];
    int t = threadIdx.x;
    int v = (t < nblk) ? bsums[t] : 0;
    sh[t] = v;
    __syncthreads();
#pragma unroll
    for (int off = 1; off < 256; off <<= 1) {
        int u = (t >= off) ? sh[t - off] : 0;
        __syncthreads();
        sh[t] += u;
        __syncthreads();
    }
    if (t < nblk) bsums[t] = sh[t] - v;
}

__global__ __launch_bounds__(256) void k_scan_p3(int* __restrict__ arr,
                                                 const int* __restrict__ bsums,
                                                 int M, int E)
{
    __shared__ int sh[256];
    int t = threadIdx.x;
    int i = blockIdx.x * 256 + t;
    int v = (i < M) ? arr[i] : 0;
    sh[t] = v;
    __syncthreads();
#pragma unroll
    for (int off = 1; off < 256; off <<= 1) {
        int u = (t >= off) ? sh[t - off] : 0;
        __syncthreads();
        sh[t] += u;
        __syncthreads();
    }
    int excl = sh[t] - v + bsums[blockIdx.x];
    if (i < M) arr[i] = excl;
    if (blockIdx.x == 0 && t == 0) arr[M] = E;
}

// ---------------------------------------------------------------------------
// KC_scatter: chunk c writes packed (dst_local<<16 | src) into its private
// per-bucket slices (LDS cursors). Requires n <= 65536.
// ---------------------------------------------------------------------------
__global__ __launch_bounds__(1024) void kc_scatter(
    const int* __restrict__ ei, int E, const int* __restrict__ flag,
    const int* __restrict__ off, int NB, int chunk, int* __restrict__ epacked)
{
    __shared__ int cur[512];
    int c = blockIdx.x;
    for (int b = threadIdx.x; b < NB; b += 1024) cur[b] = off[b * NC_CHUNK + c];
    __syncthreads();
    int base = c * chunk, end = min(E, base + chunk);
    int is64 = flag[0];
    for (int idx = base + threadIdx.x; idx < end; idx += 1024) {
        int s = is64 ? ei[2 * idx] : ei[idx];
        int d = is64 ? ei[2 * (E + idx)] : ei[E + idx];
        int p = atomicAdd(&cur[d >> 7], 1);
        epacked[p] = ((d & (BUCKET - 1)) << 16) | s;
    }
}

// ---------------------------------------------------------------------------
// KD_sort: one block per bucket. Converts the bucket's packed slice into
// per-dst CSR order (LDS hist + LDS scan + LDS-cursor scatter), writing
// sorted_src into the SAME block-private global range, and node offsets.
// ---------------------------------------------------------------------------
__global__ __launch_bounds__(256) void kd_sort(
    const int* __restrict__ off, const int* __restrict__ epacked,
    int* __restrict__ sorted_src, int* __restrict__ offsets,
    int NB, int n, int E)
{
    __shared__ int hist[BUCKET];
    __shared__ int sc[BUCKET];
    __shared__ int cur[BUCKET];
    int b = blockIdx.x;
    int s0 = off[b * NC_CHUNK];
    int s1 = off[(b + 1) * NC_CHUNK];        // b = NB-1 reads off[M] == E
    int t = threadIdx.x;
    if (t < BUCKET) hist[t] = 0;
    __syncthreads();
    for (int e = s0 + t; e < s1; e += 256)
        atomicAdd(&hist[((unsigned)epacked[e]) >> 16], 1);
    __syncthreads();
    if (t < BUCKET) sc[t] = hist[t];
    __syncthreads();
#pragma unroll
    for (int o = 1; o < BUCKET; o <<= 1) {
        int u = (t >= o && t < BUCKET) ? sc[t - o] : 0;
        __syncthreads();
        if (t < BUCKET) sc[t] += u;
        __syncthreads();
    }
    if (t < BUCKET) {
        int excl = sc[t] - hist[t];
        cur[t] = s0 + excl;
        int d = b * BUCKET + t;
        if (d < n) offsets[d] = s0 + excl;
    }
    if (b == NB - 1 && t == 0) offsets[n] = E;
    __syncthreads();
    for (int e = s0 + t; e < s1; e += 256) {
        int p = epacked[e];
        int pos = atomicAdd(&cur[((unsigned)p) >> 16], 1);
        sorted_src[pos] = p & 0xFFFF;
    }
}

// ---------------------------------------------------------------------------
// K_agg: wave-per-dst CSR gather, REGISTER accumulation (no atomics),
// unroll-8 grouped loads for MLP, fused epilogue.
// ---------------------------------------------------------------------------
__global__ __launch_bounds__(256) void k_agg(
    const int* __restrict__ offsets, const int* __restrict__ src_sorted,
    const float* __restrict__ a_s, const float* __restrict__ a_d,
    const unsigned int* __restrict__ h_bf, const float* __restrict__ r,
    const float* __restrict__ bias, const float* __restrict__ res_b,
    const float* __restrict__ ln_g, const float* __restrict__ ln_b,
    float* __restrict__ out, int n)
{
    int wv = threadIdx.x >> 6, lane = threadIdx.x & 63;
    int d = blockIdx.x * 4 + wv;
    if (d >= n) return;
    int c0 = lane * 2, head = lane >> 4;
    float ad = a_d[d * NH + head];

    // self-loop
    float e = a_s[d * NH + head] + ad;
    e = (e >= 0.f) ? e : NEG_SLOPE * e;
    float w = __expf(e);
    float denom = w;
    unsigned hv = h_bf[d * 64 + lane];
    float ax = w * __uint_as_float(hv << 16);
    float ay = w * __uint_as_float(hv & 0xffff0000u);

    int lo = offsets[d], hi = offsets[d + 1];
    int k = lo;
    for (; k + 7 < hi; k += 8) {
        int s[8]; unsigned v[8]; float ee[8];
#pragma unroll
        for (int i = 0; i < 8; ++i) s[i] = src_sorted[k + i];
#pragma unroll
        for (int i = 0; i < 8; ++i) ee[i] = a_s[s[i] * NH + head];
#pragma unroll
        for (int i = 0; i < 8; ++i) v[i] = h_bf[s[i] * 64 + lane];
#pragma unroll
        for (int i = 0; i < 8; ++i) {
            float e0 = ee[i] + ad;
            e0 = (e0 >= 0.f) ? e0 : NEG_SLOPE * e0;
            float w0 = __expf(e0);
            denom += w0;
            ax += w0 * __uint_as_float(v[i] << 16);
            ay += w0 * __uint_as_float(v[i] & 0xffff0000u);
        }
    }
    for (; k < hi; ++k) {
        int s0 = src_sorted[k];
        float e0 = a_s[s0 * NH + head] + ad;
        unsigned v0 = h_bf[s0 * 64 + lane];
        e0 = (e0 >= 0.f) ? e0 : NEG_SLOPE * e0;
        float w0 = __expf(e0);
        denom += w0;
        ax += w0 * __uint_as_float(v0 << 16);
        ay += w0 * __uint_as_float(v0 & 0xffff0000u);
    }

    float inv = 1.f / denom;
    float ox = ax * inv + bias[c0];
    float oy = ay * inv + bias[c0 + 1];
    ox = (ox > 0.f) ? ox : expm1f(ox);
    oy = (oy > 0.f) ? oy : expm1f(oy);
    float2 rv = *(const float2*)&r[d * HC + c0];
    ox += rv.x + res_b[c0];
    oy += rv.y + res_b[c0 + 1];
    float mean = wave_bcast_sum(ox + oy) * (1.f / HC);
    float dx = ox - mean, dy = oy - mean;
    float var = wave_bcast_sum(dx * dx + dy * dy) * (1.f / HC);
    float rs = rsqrtf(var + LN_EPS);
    *(float2*)&out[d * HC + c0] =
        make_float2(ln_g[c0] * dx * rs + ln_b[c0],
                    ln_g[c0 + 1] * dy * rs + ln_b[c0 + 1]);
}

// ---------------------------------------------------------------------------
extern "C" void kernel_launch(void* const* d_in, const int* in_sizes, int n_in,
                              void* d_out, int out_size, void* d_ws, size_t ws_size,
                              hipStream_t stream) {
    const float* x       = (const float*)d_in[0];
    const int*   ei      = (const int*)d_in[1];
    const float* W       = (const float*)d_in[2];
    const float* att_src = (const float*)d_in[3];
    const float* att_dst = (const float*)d_in[4];
    const float* bias    = (const float*)d_in[5];
    const float* res_w   = (const float*)d_in[6];
    const float* res_b   = (const float*)d_in[7];
    const float* ln_g    = (const float*)d_in[8];
    const float* ln_b    = (const float*)d_in[9];
    float* out = (float*)d_out;

    int n = in_sizes[0] / F_IN;              // 50000 (<= 65536 for packing)
    int E = in_sizes[1] / 2;                 // 800000
    int NB = (n + BUCKET - 1) / BUCKET;      // 391 buckets (<= 512)
    int chunk = (E + NC_CHUNK - 1) / NC_CHUNK;
    int M = NB * NC_CHUNK;                   // 50048
    int nblk = (M + 255) / 256;              // 196 (<= 256)

    float*    r        = (float*)d_ws;                     // n*HC f32
    unsigned* h_bf     = (unsigned*)(r + (size_t)n * HC);  // n*64 dwords
    float*    a_s      = (float*)(h_bf + (size_t)n * 64);  // n*NH
    float*    a_d      = a_s + (size_t)n * NH;             // n*NH
    int*      off      = (int*)(a_d + (size_t)n * NH);     // M+1
    int*      bsums    = off + (M + 1);                    // 256
    int*      epacked  = bsums + 256;                      // E
    int*      ssorted  = epacked + E;                      // E
    int*      offsets  = ssorted + E;                      // n+1
    int*      flag     = offsets + (n + 1);                // 1

    k0_detect<<<1, 256, 0, stream>>>(ei, E, flag);

    kA_gemm<<<(n + NT - 1) / NT, 256, 0, stream>>>(
        x, W, res_w, att_src, att_dst, h_bf, r, a_s, a_d, n);

    kc_count<<<NC_CHUNK, 256, 0, stream>>>(ei, E, flag, off, NB, chunk);

    k_scan_p1<<<nblk, 256, 0, stream>>>(off, M, bsums);
    k_scan_p2<<<1, 256, 0, stream>>>(bsums, nblk);
    k_scan_p3<<<nblk, 256, 0, stream>>>(off, bsums, M, E);

    kc_scatter<<<NC_CHUNK, 1024, 0, stream>>>(ei, E, flag, off, NB, chunk, epacked);

    kd_sort<<<NB, 256, 0, stream>>>(off, epacked, ssorted, offsets, NB, n, E);

    k_agg<<<(n + 3) / 4, 256, 0, stream>>>(offsets, ssorted, a_s, a_d, h_bf, r,
                                           bias, res_b, ln_g, ln_b, out, n);
}